// Round 1
// baseline (16580.667 us; speedup 1.0000x reference)
//
#include <hip/hip_runtime.h>

#define AGENT __HIP_MEMORY_SCOPE_AGENT

// ---------- helpers ----------
__device__ __forceinline__ float bflo(unsigned u){ return __uint_as_float(u<<16); }
__device__ __forceinline__ float bfhi(unsigned u){ return __uint_as_float(u & 0xffff0000u); }
__device__ __forceinline__ unsigned packbf(float a, float b){
  unsigned ua=__float_as_uint(a), ub=__float_as_uint(b);
  ua = (ua + 0x7fffu + ((ua>>16)&1u))>>16;
  ub = (ub + 0x7fffu + ((ub>>16)&1u)) & 0xffff0000u;
  return ua|ub;
}
__device__ __forceinline__ float sigf(float x){ return 1.f/(1.f+__expf(-x)); }
__device__ __forceinline__ float wredsum(float a){
  #pragma unroll
  for (int o=32;o;o>>=1) a += __shfl_xor(a,o,64);
  return a;
}

__device__ __forceinline__ void load8(const unsigned short* p, long blk, float* o){
  const uint4 v = ((const uint4*)p)[blk];
  o[0]=bflo(v.x);o[1]=bfhi(v.x);o[2]=bflo(v.y);o[3]=bfhi(v.y);
  o[4]=bflo(v.z);o[5]=bfhi(v.z);o[6]=bflo(v.w);o[7]=bfhi(v.w);
}
__device__ __forceinline__ void load8(const float* p, long blk, float* o){
  const float4 a=((const float4*)p)[blk*2], b=((const float4*)p)[blk*2+1];
  o[0]=a.x;o[1]=a.y;o[2]=a.z;o[3]=a.w;o[4]=b.x;o[5]=b.y;o[6]=b.z;o[7]=b.w;
}
__device__ __forceinline__ float2 load2(const unsigned short* p, long i){
  const unsigned u=((const unsigned*)p)[i];
  return make_float2(bflo(u), bfhi(u));
}
__device__ __forceinline__ float2 load2(const float* p, long i){ return ((const float2*)p)[i]; }

// ---------- small prep kernels ----------
__global__ void conv_bf16(const float4* __restrict__ src, uint2* __restrict__ dst, long n4){
  long i = (long)blockIdx.x*blockDim.x + threadIdx.x;
  const long st = (long)gridDim.x*blockDim.x;
  for (; i<n4; i+=st){
    const float4 v = src[i];
    dst[i] = make_uint2(packbf(v.x,v.y), packbf(v.z,v.w));
  }
}
__global__ void prep_add(const float* __restrict__ a, const float* __restrict__ b,
                         float* __restrict__ o, int n){
  int i = blockIdx.x*256+threadIdx.x;
  if (i<n) o[i]=a[i]+b[i];
}
__global__ void prep_bsum(const float* __restrict__ a,const float* __restrict__ b,
                          const float* __restrict__ c,const float* __restrict__ dd,
                          float* __restrict__ o,int n){
  int i = blockIdx.x*256+threadIdx.x;
  if (i<n) o[i]=a[i]+b[i]+c[i]+dd[i];
}

// gx0[d][row][t] = e0_wih[d][row,:] @ x[t,:] + bih + bhh
__global__ __launch_bounds__(256) void prep_gx0(
    const float* __restrict__ x, const float* __restrict__ wih,
    const float* __restrict__ bih, const float* __restrict__ bhh,
    float* __restrict__ gx)
{
  __shared__ float xl[256*27];
  const int tid = threadIdx.x;
  for (int i=tid; i<256*27; i+=256) xl[i]=x[i];
  __syncthreads();
  const long idx = (long)blockIdx.x*256 + tid;     // 32768 total
  const int tb = (int)(idx&3);
  const long rl = idx>>2;                          // 0..8191 = d*4096+row
  const float* wrow = wih + rl*27;
  float w[27];
  #pragma unroll
  for (int i=0;i<27;i++) w[i]=wrow[i];
  const float b = bih[rl]+bhh[rl];
  float* out = gx + rl*256 + tb*64;
  for (int tt=0;tt<64;tt++){
    const float* xp = xl + (tb*64+tt)*27;
    float a=b;
    #pragma unroll
    for (int i=0;i<27;i++) a += w[i]*xp[i];
    out[tt]=a;
  }
}

// ---------- fp32 tiled GEMM: C[M][N] (+ optional transposed store) = A[M][K] * B[K][N] + bias(m) ----------
template<bool TRANS>
__global__ __launch_bounds__(256) void gemm_f32(
    const float* __restrict__ A, long sAz,
    const float* __restrict__ B,
    float* __restrict__ C, long sCz,
    const float* __restrict__ b1, const float* __restrict__ b2, long sBz,
    int M, int N, int K)
{
  __shared__ float As[32][72];
  __shared__ float Bs[32][64];
  const int z = blockIdx.z;
  A += (long)z*sAz; C += (long)z*sCz;
  const float* bb1 = b1 ? b1 + (long)z*sBz : nullptr;
  const float* bb2 = b2 ? b2 + (long)z*sBz : nullptr;
  const int tid = threadIdx.x;
  const int m0 = blockIdx.y*64, n0 = blockIdx.x*64;
  const int ty = tid>>4, tx = tid&15;
  const int am = tid>>2, ak = (tid&3)*8;
  const int bk = tid>>3, bn = (tid&7)*8;
  float acc[4][4] = {};
  for (int kt=0; kt<K; kt+=32){
    float av[8], bv[8];
    const float* ap = A + (long)(m0+am)*K + kt + ak;
    const float* bp = B + (long)(kt+bk)*N + n0 + bn;
    #pragma unroll
    for (int i=0;i<8;i++) av[i]=ap[i];
    #pragma unroll
    for (int i=0;i<8;i++) bv[i]=bp[i];
    __syncthreads();
    #pragma unroll
    for (int i=0;i<8;i++) As[ak+i][am]=av[i];
    #pragma unroll
    for (int i=0;i<8;i++) Bs[bk][bn+i]=bv[i];
    __syncthreads();
    #pragma unroll
    for (int kk=0;kk<32;kk++){
      const float4 a4 = *(const float4*)&As[kk][ty*4];
      const float4 b4 = *(const float4*)&Bs[kk][tx*4];
      acc[0][0]+=a4.x*b4.x; acc[0][1]+=a4.x*b4.y; acc[0][2]+=a4.x*b4.z; acc[0][3]+=a4.x*b4.w;
      acc[1][0]+=a4.y*b4.x; acc[1][1]+=a4.y*b4.y; acc[1][2]+=a4.y*b4.z; acc[1][3]+=a4.y*b4.w;
      acc[2][0]+=a4.z*b4.x; acc[2][1]+=a4.z*b4.y; acc[2][2]+=a4.z*b4.z; acc[2][3]+=a4.z*b4.w;
      acc[3][0]+=a4.w*b4.x; acc[3][1]+=a4.w*b4.y; acc[3][2]+=a4.w*b4.z; acc[3][3]+=a4.w*b4.w;
    }
  }
  #pragma unroll
  for (int i=0;i<4;i++){
    const int m = m0+ty*4+i;
    float bias = 0.f;
    if (bb1) bias += bb1[m];
    if (bb2) bias += bb2[m];
    #pragma unroll
    for (int j=0;j<4;j++){
      const int n = n0+tx*4+j;
      const float val = acc[i][j]+bias;
      if (TRANS) C[(long)n*M + m] = val;
      else       C[(long)m*N + n] = val;
    }
  }
}

// ---------- bidirectional LSTM layer recurrence (persistent, flag-synced) ----------
// grid 256 WGs x 512 thr; WGs [0,128)=fwd dir0, [128,256)=bwd dir1. Each WG owns 8 h-elems.
__global__ __launch_bounds__(512, 2) void rec_kernel(
    const float* __restrict__ whh,   // [2][4096][1024] f32
    const float* __restrict__ gx,    // [2][4096][256]  f32 (wih@x + bih + bhh)
    float* __restrict__ seqT,        // [2048][256] f32 (row = d*1024+j, col = t)
    float* __restrict__ rowOut,      // [256][2048] f32 or null
    float* __restrict__ finalOut,    // [2][1024] (dh slots)
    float* __restrict__ hbuf,        // [2 parity][2 dir][1024]
    int* __restrict__ flags)         // [2][128]
{
  __shared__ unsigned short wlds[32*1024];
  const int wg = blockIdx.x, tid = threadIdx.x;
  const int d = wg>>7, wid = wg&127;
  // stage whh rows (bf16) into LDS; LDS row lr = jj*4 + g
  {
    const int lr = tid>>4;
    const int cs = (tid&15)*64;
    const long grow = (long)(lr&3)*1024 + wid*8 + (lr>>2);
    const float4* src = (const float4*)(whh + ((long)d*4096 + grow)*1024 + cs);
    unsigned* dst = (unsigned*)(wlds + lr*1024 + cs);
    #pragma unroll
    for (int e=0;e<16;e++){
      const float4 v = src[e];
      dst[e*2+0] = packbf(v.x,v.y);
      dst[e*2+1] = packbf(v.z,v.w);
    }
  }
  __syncthreads();
  const int lane = tid&63, wv = tid>>6;   // wave = jj
  const int q = lane>>4, c = lane&15;     // q = gate, c = col-chunk
  const int jj = wv, g = q;
  const int lr = jj*4+g;
  const int jg = wid*8 + jj;
  const long grow = (long)g*1024 + jg;
  const float* gxrow = gx + ((long)d*4096 + grow)*256;
  int* myflag = flags + d*128 + wid;
  const int* fl = flags + d*128 + (tid & 127);
  float creg = 0.f;
  for (int s=0; s<256; s++){
    const int t = d ? 255-s : s;
    if (s>0 && tid<128){
      while(__hip_atomic_load(fl, __ATOMIC_ACQUIRE, AGENT) < s) __builtin_amdgcn_s_sleep(2);
    }
    __syncthreads();
    const float gxv = (c == (t>>4)) ? gxrow[t] : 0.f;
    float acc = 0.f;
    if (s>0){
      const float4* hp4 = (const float4*)(hbuf + (((s-1)&1)*2 + d)*1024);
      const uint4* wrow = (const uint4*)(wlds + lr*1024);
      #pragma unroll
      for (int k=0;k<8;k++){
        const int blk = k*16+c;
        const uint4 w4 = wrow[blk];
        const float4 h0 = hp4[blk*2], h1 = hp4[blk*2+1];
        acc += bflo(w4.x)*h0.x + bfhi(w4.x)*h0.y + bflo(w4.y)*h0.z + bfhi(w4.y)*h0.w;
        acc += bflo(w4.z)*h1.x + bfhi(w4.z)*h1.y + bflo(w4.w)*h1.z + bfhi(w4.w)*h1.w;
      }
    }
    acc += gxv;
    #pragma unroll
    for (int o=8;o;o>>=1) acc += __shfl_xor(acc, o, 16);
    const float si = __shfl(acc, 0, 64);
    const float sf = __shfl(acc, 16, 64);
    const float sg = __shfl(acc, 32, 64);
    const float so = __shfl(acc, 48, 64);
    creg = sigf(sf)*creg + sigf(si)*tanhf(sg);
    const float h = sigf(so)*tanhf(creg);
    if (lane==0){
      hbuf[((s&1)*2 + d)*1024 + jg] = h;
      seqT[(long)(d*1024 + jg)*256 + t] = h;
      if (rowOut) rowOut[(long)t*2048 + d*1024 + jg] = h;
      if (s==255) finalOut[d*1024 + jg] = h;
    }
    __syncthreads();
    if (tid==0) __hip_atomic_store(myflag, s+1, __ATOMIC_RELEASE, AGENT);
  }
}

// ---------- decoder ----------
struct DecParams {
  float* dh; float* wsum; float* wp; float* v; float* xt; float* logits;
  const float* u; const float* encR;
  const float* att_w; const float* att_b;
  const float* o2c_w; const float* o2c_b;
  const float* ho_w; const float* ho_b;
  const float* w_b; const float* bsum;
  const float* dbias0; const float* dbias1;
  const void* wmats0; const void* wmats1; const void* wmats2; const void* wmats3; const void* wmats4;
  const void* d0wih; const void* d0whh; const void* d1wih; const void* d1whh;
  const int* maxch; float* out; int* bar;
};

__device__ void dbar_impl(int* bar, int wg, int gen){
  __syncthreads();
  if (threadIdx.x==0){
    const int leaf = wg>>4;
    int* lc = bar + leaf*32;
    int* lg = bar + 512 + leaf*32;
    int* rc = bar + 1024;
    int* rg = bar + 1040;
    if (__hip_atomic_fetch_add(lc,1,__ATOMIC_ACQ_REL,AGENT)==15){
      if (__hip_atomic_fetch_add(rc,1,__ATOMIC_ACQ_REL,AGENT)==15){
        __hip_atomic_store(rc,0,__ATOMIC_RELAXED,AGENT);
        __hip_atomic_store(rg,gen,__ATOMIC_RELEASE,AGENT);
      } else {
        while(__hip_atomic_load(rg,__ATOMIC_ACQUIRE,AGENT) < gen) __builtin_amdgcn_s_sleep(1);
      }
      __hip_atomic_store(lc,0,__ATOMIC_RELAXED,AGENT);
      __hip_atomic_store(lg,gen,__ATOMIC_RELEASE,AGENT);
    } else {
      while(__hip_atomic_load(lg,__ATOMIC_ACQUIRE,AGENT) < gen) __builtin_amdgcn_s_sleep(1);
    }
  }
  __syncthreads();
}

template<typename WT>
__global__ __launch_bounds__(256) void dec_kernel(DecParams p){
  __shared__ float rbuf[64];
  __shared__ int ibuf[8];
  const int wg = blockIdx.x, tid = threadIdx.x;
  const int lane = tid&63, wv = tid>>6;
  const int d = wg>>7, wid = wg&127;
  const int MC = *p.maxch;
  int gen = 0;
  const WT* d0wih = (const WT*)p.d0wih;
  const WT* d0whh = (const WT*)p.d0whh;
  const WT* d1wih = (const WT*)p.d1wih;
  const WT* d1whh = (const WT*)p.d1whh;
  const WT* wmats[5] = {(const WT*)p.wmats0,(const WT*)p.wmats1,(const WT*)p.wmats2,
                        (const WT*)p.wmats3,(const WT*)p.wmats4};
  float c0[2]={0.f,0.f}, c1[2]={0.f,0.f};
  float b0[2][4], b1v[2][4];
  #pragma unroll
  for (int jx=0;jx<2;jx++){
    #pragma unroll
    for (int g=0;g<4;g++){
      const int jjq = wv*2+jx;
      b0[jx][g]  = p.dbias0[d*4096 + g*1024 + wid*8 + jjq];
      b1v[jx][g] = p.dbias1[d*4096 + g*1024 + wid*8 + jjq];
    }
  }
  for (int s=0; s<MC; s++){
    const int cur = s&1, nxt = cur^1;
    // ---- S1: wsum = sum_m wm @ h[m] + bsum
    {
      const int o = wg*4 + wv;
      float a=0.f;
      #pragma unroll
      for (int m=0;m<4;m++){
        const WT* row = wmats[m] + (long)o*1024;
        const float* hm = p.dh + (cur*4+m)*1024;
        #pragma unroll
        for (int k=0;k<8;k++){
          const float2 w2 = load2(row, (long)k*64+lane);
          const float2 hh = ((const float2*)hm)[k*64+lane];
          a += w2.x*hh.x + w2.y*hh.y;
        }
      }
      a = wredsum(a);
      if (lane==0) p.wsum[o] = a + p.bsum[o];
    }
    gen++; dbar_impl(p.bar, wg, gen);
    // ---- S2: wp = w_w @ wsum + w_b
    {
      const int o = wg*4 + wv;
      const WT* row = wmats[4] + (long)o*1024;
      float a=0.f;
      #pragma unroll
      for (int k=0;k<8;k++){
        const float2 w2 = load2(row, (long)k*64+lane);
        const float2 hh = ((const float2*)p.wsum)[k*64+lane];
        a += w2.x*hh.x + w2.y*hh.y;
      }
      a = wredsum(a);
      if (lane==0) p.wp[o] = a + p.w_b[o];
    }
    gen++; dbar_impl(p.bar, wg, gen);
    // ---- S3: v[t=wg] = att_w . tanh(u[t] + wp) + att_b
    {
      const int i4 = tid*4;
      const float4 uu = *(const float4*)&p.u[(long)wg*1024 + i4];
      const float4 wq = *(const float4*)&p.wp[i4];
      const float4 aw = *(const float4*)&p.att_w[i4];
      float a = tanhf(uu.x+wq.x)*aw.x + tanhf(uu.y+wq.y)*aw.y
              + tanhf(uu.z+wq.z)*aw.z + tanhf(uu.w+wq.w)*aw.w;
      a = wredsum(a);
      if (lane==0) rbuf[wv]=a;
      __syncthreads();
      if (tid==0) p.v[wg] = rbuf[0]+rbuf[1]+rbuf[2]+rbuf[3] + p.att_b[0];
    }
    gen++; dbar_impl(p.bar, wg, gen);
    // ---- S4: argmax(prev logits) + logp write, softmax(v), cj, ins, xt
    {
      int am = 0;
      if (s>0){
        float lv = (tid<128)? p.logits[tid] : -3.0e38f;
        int li = (tid<128)? tid : (1<<20);
        #pragma unroll
        for (int o=32;o;o>>=1){
          const float ov = __shfl_xor(lv,o,64);
          const int oi = __shfl_xor(li,o,64);
          if (ov>lv || (ov==lv && oi<li)){ lv=ov; li=oi; }
        }
        if (lane==0){ rbuf[8+wv]=lv; ibuf[wv]=li; }
        __syncthreads();
        float bvv = rbuf[8]; int bii = ibuf[0];
        #pragma unroll
        for (int w2=1;w2<4;w2++){
          const float ov = rbuf[8+w2]; const int oi = ibuf[w2];
          if (ov>bvv || (ov==bvv && oi<bii)){ bvv=ov; bii=oi; }
        }
        am = bii;
        if (wg==0){
          const float e2 = (tid<128)? __expf(p.logits[tid]-bvv) : 0.f;
          float s2 = wredsum(e2);
          if (lane==0) rbuf[16+wv]=s2;
          __syncthreads();
          const float S2 = rbuf[16]+rbuf[17]+rbuf[18]+rbuf[19];
          if (tid<128) p.out[(long)(s-1)*128 + tid] = (p.logits[tid]-bvv) - logf(S2);
          __syncthreads();
        }
      }
      const float myv = p.v[tid];
      float mx = myv;
      #pragma unroll
      for (int o=32;o;o>>=1) mx = fmaxf(mx, __shfl_xor(mx,o,64));
      if (lane==0) rbuf[wv]=mx;
      __syncthreads();
      const float vmax = fmaxf(fmaxf(rbuf[0],rbuf[1]),fmaxf(rbuf[2],rbuf[3]));
      const float ee = __expf(myv - vmax);
      float s3 = wredsum(ee);
      if (lane==0) rbuf[4+wv]=s3;
      __syncthreads();
      const float vsum = rbuf[4]+rbuf[5]+rbuf[6]+rbuf[7];
      const float alpha = ee / vsum;
      const float4 e0 = *(const float4*)&p.encR[(long)tid*2048 + wg*8];
      const float4 e1 = *(const float4*)&p.encR[(long)tid*2048 + wg*8 + 4];
      float pa[8] = {alpha*e0.x, alpha*e0.y, alpha*e0.z, alpha*e0.w,
                     alpha*e1.x, alpha*e1.y, alpha*e1.z, alpha*e1.w};
      #pragma unroll
      for (int cc=0;cc<8;cc++){
        const float sc = wredsum(pa[cc]);
        if (lane==0) rbuf[24 + cc*4 + wv] = sc;
      }
      __syncthreads();
      if (tid<8){
        p.xt[2048 + wg*8 + tid] = rbuf[24+tid*4]+rbuf[24+tid*4+1]+rbuf[24+tid*4+2]+rbuf[24+tid*4+3];
      } else if (tid<16){
        const int r = wg*8 + tid-8;
        float iv = p.o2c_b[r];
        if (s>0) iv += p.o2c_w[(long)r*128 + am];
        p.xt[r] = iv;
      }
    }
    gen++; dbar_impl(p.bar, wg, gen);
    // ---- S5: decoder layer0 cells (input = xt[4096] ++ dh[cur][d])
    {
      float in[80];
      {
        const float4* xp = (const float4*)p.xt;
        #pragma unroll
        for (int k=0;k<8;k++){
          const float4 a = xp[(k*64+lane)*2];
          const float4 b2 = xp[(k*64+lane)*2+1];
          in[k*8+0]=a.x; in[k*8+1]=a.y; in[k*8+2]=a.z; in[k*8+3]=a.w;
          in[k*8+4]=b2.x; in[k*8+5]=b2.y; in[k*8+6]=b2.z; in[k*8+7]=b2.w;
        }
        const float4* hp = (const float4*)(p.dh + (cur*4+d)*1024);
        #pragma unroll
        for (int k=0;k<2;k++){
          const float4 a = hp[(k*64+lane)*2];
          const float4 b2 = hp[(k*64+lane)*2+1];
          in[64+k*8+0]=a.x; in[64+k*8+1]=a.y; in[64+k*8+2]=a.z; in[64+k*8+3]=a.w;
          in[64+k*8+4]=b2.x; in[64+k*8+5]=b2.y; in[64+k*8+6]=b2.z; in[64+k*8+7]=b2.w;
        }
      }
      #pragma unroll
      for (int jx=0;jx<2;jx++){
        const int jjq = wv*2+jx;
        float gs[4];
        #pragma unroll
        for (int g=0;g<4;g++){
          const long grow = (long)d*4096 + (long)g*1024 + wid*8 + jjq;
          const WT* wr = d0wih + grow*4096;
          const WT* hr = d0whh + grow*1024;
          float acc=0.f;
          #pragma unroll
          for (int k=0;k<8;k++){
            float w8[8]; load8(wr, (long)k*64+lane, w8);
            #pragma unroll
            for (int e=0;e<8;e++) acc += w8[e]*in[k*8+e];
          }
          #pragma unroll
          for (int k=0;k<2;k++){
            float w8[8]; load8(hr, (long)k*64+lane, w8);
            #pragma unroll
            for (int e=0;e<8;e++) acc += w8[e]*in[64+k*8+e];
          }
          gs[g] = wredsum(acc) + b0[jx][g];
        }
        c0[jx] = sigf(gs[1])*c0[jx] + sigf(gs[0])*tanhf(gs[2]);
        const float h = sigf(gs[3])*tanhf(c0[jx]);
        if (lane==0) p.dh[(nxt*4+d)*1024 + wid*8+jjq] = h;
      }
    }
    gen++; dbar_impl(p.bar, wg, gen);
    // ---- S6: decoder layer1 cells (input = dh[nxt][0..1] (=out0, 2048) ++ dh[cur][2+d])
    {
      float in2[48];
      {
        const float4* o0 = (const float4*)(p.dh + (nxt*4+0)*1024);
        #pragma unroll
        for (int k=0;k<4;k++){
          const float4 a = o0[(k*64+lane)*2];
          const float4 b2 = o0[(k*64+lane)*2+1];
          in2[k*8+0]=a.x; in2[k*8+1]=a.y; in2[k*8+2]=a.z; in2[k*8+3]=a.w;
          in2[k*8+4]=b2.x; in2[k*8+5]=b2.y; in2[k*8+6]=b2.z; in2[k*8+7]=b2.w;
        }
        const float4* hp2 = (const float4*)(p.dh + (cur*4+2+d)*1024);
        #pragma unroll
        for (int k=0;k<2;k++){
          const float4 a = hp2[(k*64+lane)*2];
          const float4 b2 = hp2[(k*64+lane)*2+1];
          in2[32+k*8+0]=a.x; in2[32+k*8+1]=a.y; in2[32+k*8+2]=a.z; in2[32+k*8+3]=a.w;
          in2[32+k*8+4]=b2.x; in2[32+k*8+5]=b2.y; in2[32+k*8+6]=b2.z; in2[32+k*8+7]=b2.w;
        }
      }
      #pragma unroll
      for (int jx=0;jx<2;jx++){
        const int jjq = wv*2+jx;
        float gs[4];
        #pragma unroll
        for (int g=0;g<4;g++){
          const long grow = (long)d*4096 + (long)g*1024 + wid*8 + jjq;
          const WT* wr = d1wih + grow*2048;
          const WT* hr = d1whh + grow*1024;
          float acc=0.f;
          #pragma unroll
          for (int k=0;k<4;k++){
            float w8[8]; load8(wr, (long)k*64+lane, w8);
            #pragma unroll
            for (int e=0;e<8;e++) acc += w8[e]*in2[k*8+e];
          }
          #pragma unroll
          for (int k=0;k<2;k++){
            float w8[8]; load8(hr, (long)k*64+lane, w8);
            #pragma unroll
            for (int e=0;e<8;e++) acc += w8[e]*in2[32+k*8+e];
          }
          gs[g] = wredsum(acc) + b1v[jx][g];
        }
        c1[jx] = sigf(gs[1])*c1[jx] + sigf(gs[0])*tanhf(gs[2]);
        const float h = sigf(gs[3])*tanhf(c1[jx]);
        if (lane==0) p.dh[(nxt*4+2+d)*1024 + wid*8+jjq] = h;
      }
    }
    gen++; dbar_impl(p.bar, wg, gen);
    // ---- S7: logits (128 WGs, one row each)
    {
      if (wg<128){
        const float* ov = p.dh + (nxt*4+2)*1024;
        const int c8 = tid*8;
        const float4 h0=*(const float4*)&ov[c8], h1=*(const float4*)&ov[c8+4];
        const float4 w0=*(const float4*)&p.ho_w[(long)wg*2048 + c8];
        const float4 w1=*(const float4*)&p.ho_w[(long)wg*2048 + c8+4];
        float a = h0.x*w0.x+h0.y*w0.y+h0.z*w0.z+h0.w*w0.w
                + h1.x*w1.x+h1.y*w1.y+h1.z*w1.z+h1.w*w1.w;
        a = wredsum(a);
        if (lane==0) rbuf[wv]=a;
        __syncthreads();
        if (tid==0) p.logits[wg] = rbuf[0]+rbuf[1]+rbuf[2]+rbuf[3] + p.ho_b[wg];
      }
    }
    gen++; dbar_impl(p.bar, wg, gen);
  }
  // tail: logp for the last step
  if (wg==0){
    float lv = (tid<128)? p.logits[tid] : -3.0e38f;
    float mx = lv;
    #pragma unroll
    for (int o=32;o;o>>=1) mx = fmaxf(mx,__shfl_xor(mx,o,64));
    if (lane==0) rbuf[wv]=mx;
    __syncthreads();
    const float M2 = fmaxf(fmaxf(rbuf[0],rbuf[1]),fmaxf(rbuf[2],rbuf[3]));
    const float e2 = (tid<128)? __expf(p.logits[tid]-M2):0.f;
    float s2 = wredsum(e2);
    if (lane==0) rbuf[4+wv]=s2;
    __syncthreads();
    const float S2 = rbuf[4]+rbuf[5]+rbuf[6]+rbuf[7];
    if (tid<128) p.out[(long)(MC-1)*128 + tid] = (p.logits[tid]-M2) - logf(S2);
  }
}

// ---------- host ----------
extern "C" void kernel_launch(void* const* d_in, const int* in_sizes, int n_in,
                              void* d_out, int out_size, void* d_ws, size_t ws_size,
                              hipStream_t stream){
  const float* x      = (const float*)d_in[0];
  const int*   maxch  = (const int*)d_in[1];
  const float* e0_wih = (const float*)d_in[2];
  const float* e0_whh = (const float*)d_in[3];
  const float* e0_bih = (const float*)d_in[4];
  const float* e0_bhh = (const float*)d_in[5];
  const float* e1_wih = (const float*)d_in[6];
  const float* e1_whh = (const float*)d_in[7];
  const float* e1_bih = (const float*)d_in[8];
  const float* e1_bhh = (const float*)d_in[9];
  const float* d0_wih = (const float*)d_in[10];
  const float* d0_whh = (const float*)d_in[11];
  const float* d0_bih = (const float*)d_in[12];
  const float* d0_bhh = (const float*)d_in[13];
  const float* d1_wih = (const float*)d_in[14];
  const float* d1_whh = (const float*)d_in[15];
  const float* d1_bih = (const float*)d_in[16];
  const float* d1_bhh = (const float*)d_in[17];
  const float* u_w    = (const float*)d_in[18];
  const float* u_b    = (const float*)d_in[19];
  const float* w1_w   = (const float*)d_in[20];
  const float* w1_b   = (const float*)d_in[21];
  const float* w2_w   = (const float*)d_in[22];
  const float* w2_b   = (const float*)d_in[23];
  const float* w3_w   = (const float*)d_in[24];
  const float* w3_b   = (const float*)d_in[25];
  const float* w4_w   = (const float*)d_in[26];
  const float* w4_b   = (const float*)d_in[27];
  const float* w_w    = (const float*)d_in[28];
  const float* w_b    = (const float*)d_in[29];
  const float* att_w  = (const float*)d_in[30];
  const float* att_b  = (const float*)d_in[31];
  const float* o2c_w  = (const float*)d_in[32];
  const float* o2c_b  = (const float*)d_in[33];
  const float* ho_w   = (const float*)d_in[34];
  const float* ho_b   = (const float*)d_in[35];

  char* ws = (char*)d_ws;
  size_t off = 0;
  auto alloc = [&](size_t n)->char*{ char* p = ws + off; off = (off + n + 255) & ~(size_t)255; return p; };
  int*   ctrl   = (int*)  alloc(8192);
  float* hbuf0  = (float*)alloc((size_t)2*2*1024*4);
  float* hbuf1  = (float*)alloc((size_t)2*2*1024*4);
  float* seqT0  = (float*)alloc((size_t)2048*256*4);
  float* gx0    = (float*)alloc((size_t)2*4096*256*4);
  float* gx1    = (float*)alloc((size_t)2*4096*256*4);
  float* encT   = (float*)alloc((size_t)2048*256*4);
  float* encR   = (float*)alloc((size_t)256*2048*4);
  float* u      = (float*)alloc((size_t)256*1024*4);
  float* dh     = (float*)alloc((size_t)2*4*1024*4);
  float* wsum   = (float*)alloc(1024*4);
  float* wp     = (float*)alloc(1024*4);
  float* v      = (float*)alloc(256*4);
  float* xt     = (float*)alloc(4096*4);
  float* logits = (float*)alloc(128*4);
  float* dbias0 = (float*)alloc((size_t)2*4096*4);
  float* dbias1 = (float*)alloc((size_t)2*4096*4);
  float* bsum   = (float*)alloc(1024*4);
  const size_t f32_end = off;
  unsigned short* b_d0wih = (unsigned short*)alloc((size_t)2*4096*4096*2);
  unsigned short* b_d0whh = (unsigned short*)alloc((size_t)2*4096*1024*2);
  unsigned short* b_d1wih = (unsigned short*)alloc((size_t)2*4096*2048*2);
  unsigned short* b_d1whh = (unsigned short*)alloc((size_t)2*4096*1024*2);
  unsigned short* b_w5    = (unsigned short*)alloc((size_t)5*1024*1024*2);
  const bool useB16 = (ws_size >= off);
  if (ws_size < f32_end) return;

  hipMemsetAsync(ctrl, 0, 8192, stream);
  prep_add<<<dim3(32),256,0,stream>>>(d0_bih, d0_bhh, dbias0, 8192);
  prep_add<<<dim3(32),256,0,stream>>>(d1_bih, d1_bhh, dbias1, 8192);
  prep_bsum<<<dim3(4),256,0,stream>>>(w1_b, w2_b, w3_b, w4_b, bsum, 1024);
  if (useB16){
    conv_bf16<<<2048,256,0,stream>>>((const float4*)d0_wih, (uint2*)b_d0wih, (long)2*4096*4096/4);
    conv_bf16<<<1024,256,0,stream>>>((const float4*)d0_whh, (uint2*)b_d0whh, (long)2*4096*1024/4);
    conv_bf16<<<2048,256,0,stream>>>((const float4*)d1_wih, (uint2*)b_d1wih, (long)2*4096*2048/4);
    conv_bf16<<<1024,256,0,stream>>>((const float4*)d1_whh, (uint2*)b_d1whh, (long)2*4096*1024/4);
    conv_bf16<<<256,256,0,stream>>>((const float4*)w1_w, (uint2*)(b_w5+0*1048576), 1048576/4);
    conv_bf16<<<256,256,0,stream>>>((const float4*)w2_w, (uint2*)(b_w5+1*1048576), 1048576/4);
    conv_bf16<<<256,256,0,stream>>>((const float4*)w3_w, (uint2*)(b_w5+2*1048576), 1048576/4);
    conv_bf16<<<256,256,0,stream>>>((const float4*)w4_w, (uint2*)(b_w5+3*1048576), 1048576/4);
    conv_bf16<<<256,256,0,stream>>>((const float4*)w_w,  (uint2*)(b_w5+4*1048576), 1048576/4);
  }
  prep_gx0<<<128,256,0,stream>>>(x, e0_wih, e0_bih, e0_bhh, gx0);
  // encoder layer 0
  rec_kernel<<<256,512,0,stream>>>(e0_whh, gx0, seqT0, nullptr, dh, hbuf0, ctrl+0);
  // layer-1 input projections: gx1[d] = e1_wih[d] @ h0out^T + biases
  gemm_f32<false><<<dim3(4,64,2),256,0,stream>>>(e1_wih, (long)4096*2048, seqT0,
      gx1, (long)4096*256, e1_bih, e1_bhh, 4096, 4096, 256, 2048);
  // encoder layer 1
  rec_kernel<<<256,512,0,stream>>>(e1_whh, gx1, encT, encR, dh+2*1024, hbuf1, ctrl+256);
  // u[t][o] = enc[t] . u_w[o] + u_b
  gemm_f32<true><<<dim3(4,16,1),256,0,stream>>>(u_w, 0, encT, u, 0, u_b, nullptr, 0, 1024, 256, 2048);

  DecParams P;
  P.dh=dh; P.wsum=wsum; P.wp=wp; P.v=v; P.xt=xt; P.logits=logits;
  P.u=u; P.encR=encR; P.att_w=att_w; P.att_b=att_b;
  P.o2c_w=o2c_w; P.o2c_b=o2c_b; P.ho_w=ho_w; P.ho_b=ho_b;
  P.w_b=w_b; P.bsum=bsum; P.dbias0=dbias0; P.dbias1=dbias1;
  P.maxch=maxch; P.out=(float*)d_out; P.bar=ctrl+512;
  if (useB16){
    P.wmats0=b_w5+0*1048576; P.wmats1=b_w5+1*1048576; P.wmats2=b_w5+2*1048576;
    P.wmats3=b_w5+3*1048576; P.wmats4=b_w5+4*1048576;
    P.d0wih=b_d0wih; P.d0whh=b_d0whh; P.d1wih=b_d1wih; P.d1whh=b_d1whh;
    dec_kernel<unsigned short><<<256,256,0,stream>>>(P);
  } else {
    P.wmats0=w1_w; P.wmats1=w2_w; P.wmats2=w3_w; P.wmats3=w4_w; P.wmats4=w_w;
    P.d0wih=d0_wih; P.d0whh=d0_whh; P.d1wih=d1_wih; P.d1whh=d1_whh;
    dec_kernel<float><<<256,256,0,stream>>>(P);
  }
}